// Round 8
// baseline (322.333 us; speedup 1.0000x reference)
//
#include <hip/hip_runtime.h>

// CosformerAttention on MI355X (gfx950). Inputs fp32, OUTPUT fp32.
// B=8, E=768, L=48*48=2304, heads=12, d=64, n=B*h=96, M=L*B=18432.
//
// Round-15: round-14 (kv_fused, k/v HBM round-trip eliminated) with the
// gemm256<1> launch-arg compile fix (dstb=nullptr, dstf=out).

#define L_SEQ 2304
#define BATCH 8
#define EDIM 768
#define NHEAD 12
#define DHEAD 64
#define MROWS (L_SEQ * BATCH)  // 18432

typedef __attribute__((ext_vector_type(8))) short bf16x8_t;   // 8 bf16 = 4 VGPRs
typedef __attribute__((ext_vector_type(4))) float f32x4_t;

__device__ __forceinline__ float b2f(unsigned short u) {
  union { unsigned int i; float f; } x; x.i = ((unsigned int)u) << 16; return x.f;
}
__device__ __forceinline__ unsigned short f2b(float f) {
  union { float f; unsigned int i; } x; x.f = f;
  unsigned int r = x.i + 0x7FFFu + ((x.i >> 16) & 1u);  // RNE
  return (unsigned short)(r >> 16);
}

// async 16B global->LDS (gfx950; wave-uniform base + lane*16 dest contract)
#define GLOAD_LDS16(g, l)                                                     \
  __builtin_amdgcn_global_load_lds(                                           \
      (const __attribute__((address_space(1))) unsigned int*)(g),             \
      (__attribute__((address_space(3))) unsigned int*)(l), 16, 0, 0)

#define BAR() __builtin_amdgcn_s_barrier()
#define SB0() __builtin_amdgcn_sched_barrier(0)
#define LGKM0() asm volatile("s_waitcnt lgkmcnt(0)")
#define LGKM0M() asm volatile("s_waitcnt lgkmcnt(0)" ::: "memory")
#define VMW(N) asm volatile("s_waitcnt vmcnt(" #N ")" ::: "memory")

// ---------------------------------------------------------------------------
// Kernel 0 (merged): blocks [0,2304): conv 4 fp32 weight mats -> bf16.
//                    blocks [2304,5760): transpose query (B,E,L) -> xT bf16.
//                    blocks [5760,6540): zero kvT + ksum (3,194,880 B).
//                    blocks [6540,6549): sin/cos table sct[l], l in [0,2304).
__global__ __launch_bounds__(256) void prep(
    const float* __restrict__ q,
    const float* __restrict__ W0, const float* __restrict__ W1,
    const float* __restrict__ W2, const float* __restrict__ W3,
    unsigned short* __restrict__ wbf, unsigned short* __restrict__ xT,
    float* __restrict__ kvz, float2* __restrict__ sct) {
  __shared__ float tile[64][65];
  int bx = blockIdx.x;
  int t = threadIdx.x;
  if (bx < 2304) {
    int y = bx / 576;
    const float* W = (y == 0) ? W0 : (y == 1) ? W1 : (y == 2) ? W2 : W3;
    unsigned short* d = wbf + (size_t)y * EDIM * EDIM;
    int idx = (bx - y * 576) * 256 + t;  // [0, 147456)
    float4 v = *(const float4*)(W + (size_t)idx * 4);
    ushort4 o;
    o.x = f2b(v.x); o.y = f2b(v.y); o.z = f2b(v.z); o.w = f2b(v.w);
    *(ushort4*)(d + (size_t)idx * 4) = o;
  } else if (bx < 5760) {
    int bb = bx - 2304;           // 12 x 36 x 8
    int e0 = (bb % 12) * 64;
    int l0 = ((bb / 12) % 36) * 64;
    int b = bb / 432;
    int li = t & 63, er = t >> 6;
#pragma unroll
    for (int p = 0; p < 16; p++) {
      int eo = er + p * 4;
      tile[eo][li] = q[((size_t)b * EDIM + (e0 + eo)) * L_SEQ + (l0 + li)];
    }
    __syncthreads();
    int ei = t & 63, lr = t >> 6;
#pragma unroll
    for (int p = 0; p < 16; p++) {
      int lo = lr + p * 4;
      xT[((size_t)b * L_SEQ + (l0 + lo)) * EDIM + (e0 + ei)] = f2b(tile[ei][lo]);
    }
  } else if (bx < 6540) {
    int idx = (bx - 5760) * 256 + t;  // [0, 199680) float4s
    *(float4*)(kvz + (size_t)idx * 4) = make_float4(0.f, 0.f, 0.f, 0.f);
  } else {
    int l = (bx - 6540) * 256 + t;    // [0, 2304)
    if (l < L_SEQ) {
      float sv, cv;
      sincosf(1.5707963267948966f * (float)(l + 1) / 2304.0f, &sv, &cv);
      sct[l] = make_float2(sv, cv);
    }
  }
}

// ---------------------------------------------------------------------------
// Kernel 1/4: C = A @ W^T (+bias, opt relu). 128x128 tile, BK=64, 512 thr
// (8 waves, 2Mx4N, 64x32 out/wave), 2-phase double-buffered K-loop,
// 64 KiB dynamic LDS, 2 blk/CU. MODE 0: q projection (bf16 head layout,
// relu). MODE 1: output projection (fp32). Grid 864 = 144 x 6 both.
#define ABUF(b_) ((b_) * 8192)
#define BBUF(b_) (16384 + (b_) * 8192)

#define STG_AB(kt_, B_)                                                       \
  {                                                                           \
    GLOAD_LDS16(a_sb + (size_t)(kt_) * 64, lds + ABUF(B_) + t * 8);           \
    GLOAD_LDS16(a_sb + (size_t)64 * EDIM + (size_t)(kt_) * 64,                \
                lds + ABUF(B_) + 4096 + t * 8);                               \
    GLOAD_LDS16(b_sb + (size_t)(kt_) * 64, lds + BBUF(B_) + t * 8);           \
    GLOAD_LDS16(b_sb + (size_t)64 * EDIM + (size_t)(kt_) * 64,                \
                lds + BBUF(B_) + 4096 + t * 8);                               \
  }

#define DS_RD(B_)                                                             \
  _Pragma("unroll") for (int m_ = 0; m_ < 4; m_++)                            \
  _Pragma("unroll") for (int kk_ = 0; kk_ < 2; kk_++)                         \
    aF[m_][kk_] = *(const bf16x8_t*)(lds + ABUF(B_) +                         \
        ((a_base + (m_ >> 1) * 4096 + (m_ & 1) * 1024 + kk_ * 32) ^ xorv));   \
  _Pragma("unroll") for (int n_ = 0; n_ < 2; n_++)                            \
  _Pragma("unroll") for (int kk_ = 0; kk_ < 2; kk_++)                         \
    bF[n_][kk_] = *(const bf16x8_t*)(lds + BBUF(B_) +                         \
        ((b_base + n_ * 4096 + kk_ * 32) ^ xorv));

#define MFMA16()                                                              \
  __builtin_amdgcn_s_setprio(1);                                              \
  _Pragma("unroll") for (int m_ = 0; m_ < 4; m_++)                            \
  _Pragma("unroll") for (int n_ = 0; n_ < 2; n_++)                            \
  _Pragma("unroll") for (int kk_ = 0; kk_ < 2; kk_++)                         \
    acc[m_][n_] = __builtin_amdgcn_mfma_f32_16x16x32_bf16(                    \
        aF[m_][kk_], bF[n_][kk_], acc[m_][n_], 0, 0, 0);                      \
  __builtin_amdgcn_s_setprio(0);

template <int MODE>
__global__ __launch_bounds__(512, 4) void gemm256(
    const unsigned short* __restrict__ A,
    const unsigned short* __restrict__ W,
    const float* __restrict__ bias,
    unsigned short* __restrict__ dstb,   // MODE 0: bf16 head layout
    float* __restrict__ dstf) {          // MODE 1: fp32
  extern __shared__ __align__(16) unsigned short lds[];

  int rowblk, colblk;
  {
    int nwg = (int)gridDim.x;            // 864, % 8 == 0
    int wg = ((int)blockIdx.x & 7) * (nwg >> 3) + ((int)blockIdx.x >> 3);
    rowblk = wg / 6;
    colblk = wg - rowblk * 6;
  }
  const int row0 = rowblk * 128;
  const int col0 = colblk * 128;

  const int t = threadIdx.x;
  const int lane = t & 63;
  const int wave = t >> 6;
  const int wm = wave >> 2;
  const int wn = wave & 3;
  const int mrow = lane & 15;
  const int quad = lane >> 4;

  const int xorv = (mrow & 7) << 3;
  const int a_base = (wm * 32 + mrow) * 64 + quad * 8;
  const int b_base = (wn * 16 + mrow) * 64 + quad * 8;

  const int lr_s = t >> 3;
  const int k0_s = ((((t >> 3) & 7) ^ (t & 7)) << 3);
  const unsigned short* a_sb = A + (size_t)(row0 + lr_s) * EDIM + k0_s;
  const unsigned short* b_sb = W + (size_t)(col0 + lr_s) * EDIM + k0_s;

  f32x4_t acc[4][2] = {};
  bf16x8_t aF[4][2], bF[2][2];

  STG_AB(0, 0);
  STG_AB(1, 1);
  VMW(4);
  BAR();

#pragma unroll
  for (int i = 0; i < 12; ++i) {     // K = 768 = 12 K-tiles x BK=64
    const int cur = i & 1;
    DS_RD(cur);
    SB0();
    LGKM0();
    BAR();
    if (i < 10) STG_AB(i + 2, cur);
    MFMA16();
    if (i < 10) { VMW(4); } else { VMW(0); }
    BAR();
  }

  const int bb = row0 / L_SEQ;
#pragma unroll
  for (int ti = 0; ti < 4; ti++) {
    int rbase = row0 + (ti >> 1) * 64 + wm * 32 + (ti & 1) * 16 + quad * 4;
#pragma unroll
    for (int tj = 0; tj < 2; tj++) {
      int gc = col0 + tj * 64 + wn * 16 + mrow;
      float bv = bias[gc];
#pragma unroll
      for (int r = 0; r < 4; r++) {
        int gr = rbase + r;
        float v = acc[ti][tj][r] + bv;
        if (MODE == 0) {
          v = fmaxf(v, 0.0f);  // q: relu
          int ll = gr - bb * L_SEQ;
          int n = bb * NHEAD + (gc >> 6);
          dstb[((size_t)n * L_SEQ + ll) * DHEAD + (gc & 63)] = f2b(v);
        } else {
          dstf[(size_t)gr * EDIM + gc] = v;  // FP32 output
        }
      }
    }
  }
}

// ---------------------------------------------------------------------------
// Kernel 2: kv_fused. One block per (head n, l-chunk c of 768).
// Per l-tile (128 rows): 2-phase GEMM K-loop (A=xT rows, B=[Wk|Wv] head
// rows) -> k,v in regs; bias+relu+sin/cos; transpose-stage to ksT/vsT
// (stride 72, 16B-aligned); per-64-l-slice MFMA accumulate into persistent
// accKV (A=vsT m-tiles, B=ksT j-tiles; validated kv_mfma orientation).
// ksum via per-thread f32 partials. Single atomic drain at end.
//
// Dynamic LDS (ushort elems): Al=2x8192 @0, Bl=2x8192 @16384,
// ksT[128*72] @32768, vsT[64*72] @41984, ksum_l(float[128]) @46592.
// Total 93,696 B.
#define KAB(b_) ((b_) * 8192)
#define KBB(b_) (16384 + (b_) * 8192)
#define KST 32768
#define VST 41984
#define ST2 72

#define KSTG(srow_, kt_, B_)                                                  \
  {                                                                           \
    GLOAD_LDS16(a_sb + (size_t)(srow_) * EDIM + (kt_) * 64,                   \
                lds + KAB(B_) + t * 8);                                       \
    GLOAD_LDS16(a_sb + (size_t)((srow_) + 64) * EDIM + (kt_) * 64,            \
                lds + KAB(B_) + 4096 + t * 8);                                \
    GLOAD_LDS16(wk_sb + (kt_) * 64, lds + KBB(B_) + t * 8);                   \
    GLOAD_LDS16(wv_sb + (kt_) * 64, lds + KBB(B_) + 4096 + t * 8);            \
  }

#define KDS_RD(B_)                                                            \
  _Pragma("unroll") for (int m_ = 0; m_ < 4; m_++)                            \
  _Pragma("unroll") for (int kk_ = 0; kk_ < 2; kk_++)                         \
    aF[m_][kk_] = *(const bf16x8_t*)(lds + KAB(B_) +                          \
        ((a_base + (m_ >> 1) * 4096 + (m_ & 1) * 1024 + kk_ * 32) ^ xorv));   \
  _Pragma("unroll") for (int n_ = 0; n_ < 2; n_++)                            \
  _Pragma("unroll") for (int kk_ = 0; kk_ < 2; kk_++)                         \
    bF[n_][kk_] = *(const bf16x8_t*)(lds + KBB(B_) +                          \
        ((b_base + n_ * 4096 + kk_ * 32) ^ xorv));

__global__ __launch_bounds__(512, 2) void kv_fused(
    const unsigned short* __restrict__ xT, const unsigned short* __restrict__ wbf,
    const float* __restrict__ bk, const float* __restrict__ bv,
    const float2* __restrict__ sct,
    float* __restrict__ kvT, float* __restrict__ ksum) {
  extern __shared__ __align__(16) unsigned short lds[];
  float* ksum_l = (float*)(lds + 46592);

  int bx = blockIdx.x;
  int n = bx / 3, c = bx - n * 3;     // head, l-chunk (768 rows)
  int b = n / NHEAD, hd = n % NHEAD;

  const int t = threadIdx.x;
  const int lane = t & 63;
  const int wave = t >> 6;
  const int wm = wave >> 2;
  const int wn = wave & 3;
  const int mrow = lane & 15;
  const int quad = lane >> 4;

  const int xorv = (mrow & 7) << 3;
  const int a_base = (wm * 32 + mrow) * 64 + quad * 8;
  const int b_base = (wn * 16 + mrow) * 64 + quad * 8;

  const int lr_s = t >> 3;
  const int k0_s = ((((t >> 3) & 7) ^ (t & 7)) << 3);
  const unsigned short* a_sb =
      xT + ((size_t)(b * L_SEQ + c * 768) + lr_s) * EDIM + k0_s;
  const unsigned short* wk_sb =
      wbf + (size_t)EDIM * EDIM + (size_t)(hd * 64 + lr_s) * EDIM + k0_s;
  const unsigned short* wv_sb =
      wbf + (size_t)2 * EDIM * EDIM + (size_t)(hd * 64 + lr_s) * EDIM + k0_s;

  const int colh = wn * 16 + mrow;     // 0..63 (feature col within head)
  const float bkv = bk[hd * 64 + colh];
  const float bvv = bv[hd * 64 + colh];

  if (t < 128) ksum_l[t] = 0.f;

  const int mt = wave & 3;             // vsT m-tile owned by this wave
  const int j0 = (wave >> 2) * 4;      // ksT j-tile group (4 tiles)
  f32x4_t accKV[4] = {};
  float sks = 0.f, skc = 0.f;

  bf16x8_t aF[4][2], bF[2][2];

  // prologue: lt=0 kt0 -> buf0, kt1 -> buf1
  KSTG(0, 0, 0);
  KSTG(0, 1, 1);
  VMW(4);
  BAR();

  for (int lt = 0; lt < 6; lt++) {
    f32x4_t acc[4][2] = {};
#pragma unroll
    for (int i = 0; i < 12; ++i) {
      const int cur = i & 1;
      KDS_RD(cur);
      SB0();
      LGKM0();
      BAR();
      const bool stg = (lt < 5) || (i < 10);
      if (stg) {
        int srow = ((i < 10) ? lt : (lt + 1)) * 128;
        const int skt = (i + 2) % 12;
        KSTG(srow, skt, cur);
      }
      MFMA16();
      if (stg) { VMW(4); } else { VMW(0); }
      BAR();
    }

    // --- transpose-stage + kv-MFMA, two 64-l slices ---
#pragma unroll
    for (int sl = 0; sl < 2; sl++) {
#pragma unroll
      for (int mi = 0; mi < 2; mi++) {
        const int m_ = sl * 2 + mi;
        const int lrow = wm * 32 + mi * 16 + quad * 4;       // +r in [0,64)
        const int gl = c * 768 + lt * 128 + sl * 64 + lrow;  // global seq pos
        ushort4 pks, pkc, pv;
#pragma unroll
        for (int r = 0; r < 4; r++) {
          float2 sc = sct[gl + r];
          float kvl = fmaxf(acc[m_][0][r] + bkv, 0.f);   // relu(k + bk)
          float a = kvl * sc.x, cc = kvl * sc.y;
          sks += a; skc += cc;
          ((unsigned short*)&pks)[r] = f2b(a);
          ((unsigned short*)&pkc)[r] = f2b(cc);
          ((unsigned short*)&pv)[r] = f2b(acc[m_][1][r] + bvv);
        }
        *(ushort4*)(lds + KST + (colh * ST2 + lrow)) = pks;
        *(ushort4*)(lds + KST + ((64 + colh) * ST2 + lrow)) = pkc;
        *(ushort4*)(lds + VST + (colh * ST2 + lrow)) = pv;
      }
      SB0();
      LGKM0M();
      BAR();
      SB0();
      {
        bf16x8_t av[2];
#pragma unroll
        for (int kk = 0; kk < 2; kk++)
          av[kk] = *(const bf16x8_t*)(lds + VST +
                                      ((mt * 16 + mrow) * ST2 + kk * 32 + quad * 8));
#pragma unroll
        for (int jj = 0; jj < 4; jj++) {
#pragma unroll
          for (int kk = 0; kk < 2; kk++) {
            bf16x8_t bk8 = *(const bf16x8_t*)(lds + KST +
                (((j0 + jj) * 16 + mrow) * ST2 + kk * 32 + quad * 8));
            accKV[jj] = __builtin_amdgcn_mfma_f32_16x16x32_bf16(
                av[kk], bk8, accKV[jj], 0, 0, 0);
          }
        }
      }
      SB0();
      LGKM0M();
      BAR();
      SB0();
    }
  }

  // --- drain: ksum (LDS reduce -> global atomic), kvT atomics ---
  atomicAdd(&ksum_l[colh], sks);
  atomicAdd(&ksum_l[64 + colh], skc);
  __syncthreads();
  if (t < 128) atomicAdd(&ksum[n * 128 + t], ksum_l[t]);

#pragma unroll
  for (int jj = 0; jj < 4; jj++) {
#pragma unroll
    for (int r = 0; r < 4; r++) {
      int m = mt * 16 + quad * 4 + r;
      int j = (j0 + jj) * 16 + mrow;
      atomicAdd(&kvT[((size_t)n * 64 + m) * 128 + j], accKV[jj][r]);
    }
  }
}

// ---------------------------------------------------------------------------
// Kernel 3 (MFMA): C0 = q@kv0, C1 = q@kv1; out = zs*C0 + zc*C1; fused
// residual + relayout. (unchanged from round-11)
__global__ __launch_bounds__(256) void attn_mfma(
    const unsigned short* __restrict__ qbuf, const float* __restrict__ kvT,
    const float* __restrict__ ksum, const unsigned short* __restrict__ xT,
    const float2* __restrict__ sct,
    unsigned short* __restrict__ attn) {
  __shared__ __align__(16) unsigned short As[128 * 72];
  __shared__ __align__(16) unsigned short Bs[64 * 136];
  __shared__ float ks_l[128];
  __shared__ float zs[128], zc[128];
  int l0 = blockIdx.x * 128;
  int n = blockIdx.y;
  int t = threadIdx.x;
  int lane = t & 63, wave = t >> 6;
  int mrow = lane & 15, quad = lane >> 4;
  int b = n / NHEAD, hd = n % NHEAD;

  {
    int row = t >> 1, off = (t & 1) * 32;
    const unsigned short* src = qbuf + ((size_t)n * L_SEQ + l0 + row) * DHEAD + off;
    unsigned short* d = As + row * 72 + off;
#pragma unroll
    for (int c = 0; c < 4; c++)
      *(uint4*)(d + c * 8) = *(const uint4*)(src + c * 8);
  }
  {
    int m = t >> 2, part = t & 3;  // Bs[m][j] = f2b(kvT[n][m][j]) -- coalesced
    const float* src = kvT + ((size_t)n * 64 + m) * 128 + part * 32;
    unsigned short* dBs = Bs + m * 136 + part * 32;
#pragma unroll
    for (int c = 0; c < 4; c++) {
      float4 a = *(const float4*)(src + c * 8);
      float4 bq = *(const float4*)(src + c * 8 + 4);
      ushort4 o1, o2;
      o1.x = f2b(a.x); o1.y = f2b(a.y); o1.z = f2b(a.z); o1.w = f2b(a.w);
      o2.x = f2b(bq.x); o2.y = f2b(bq.y); o2.z = f2b(bq.z); o2.w = f2b(bq.w);
      *(ushort4*)(dBs + c * 8) = o1;
      *(ushort4*)(dBs + c * 8 + 4) = o2;
    }
  }
  if (t < 128) ks_l[t] = ksum[n * 128 + t];
  __syncthreads();

  if (t < 128) {
    float d0 = 0.f, d1 = 0.f;
    const unsigned short* arow = As + t * 72;
#pragma unroll
    for (int j = 0; j < 8; j++) {
      bf16x8_t v = *(const bf16x8_t*)(arow + j * 8);
#pragma unroll
      for (int e = 0; e < 8; e++) {
        float qv = b2f((unsigned short)v[e]);
        d0 += qv * ks_l[j * 8 + e];
        d1 += qv * ks_l[64 + j * 8 + e];
      }
    }
    float2 sc = sct[l0 + t];
    float z = 1.0f / fmaxf(sc.x * d0 + sc.y * d1, 1e-6f);
    zs[t] = z * sc.x;
    zc[t] = z * sc.y;
  }
  __syncthreads();

  int wr = wave * 32;
  f32x4_t acc0[2][4] = {}, acc1[2][4] = {};
#pragma unroll
  for (int ks = 0; ks < 2; ks++) {
    bf16x8_t af[2];
#pragma unroll
    for (int ti = 0; ti < 2; ti++)
      af[ti] = *(const bf16x8_t*)(As + (wr + ti * 16 + mrow) * 72 + ks * 32 + quad * 8);
#pragma unroll
    for (int tj = 0; tj < 4; tj++) {
      bf16x8_t b0 = *(const bf16x8_t*)(Bs + (tj * 16 + mrow) * 136 + ks * 32 + quad * 8);
      bf16x8_t b1 = *(const bf16x8_t*)(Bs + (tj * 16 + mrow) * 136 + 64 + ks * 32 + quad * 8);
#pragma unroll
      for (int ti = 0; ti < 2; ti++) {
        acc0[ti][tj] = __builtin_amdgcn_mfma_f32_16x16x32_bf16(af[ti], b0, acc0[ti][tj], 0, 0, 0);
        acc1[ti][tj] = __builtin_amdgcn_mfma_f32_16x16x32_bf16(af[ti], b1, acc1[ti][tj], 0, 0, 0);
      }
    }
  }

#pragma unroll
  for (int ti = 0; ti < 2; ti++) {
#pragma unroll
    for (int tj = 0; tj < 4; tj++) {
      int m = tj * 16 + mrow;
#pragma unroll
      for (int r = 0; r < 4; r++) {
        int row = wr + ti * 16 + quad * 4 + r;
        int l = l0 + row;
        float ov = zs[row] * acc0[ti][tj][r] + zc[row] * acc1[ti][tj][r];
        float xv = b2f(xT[((size_t)b * L_SEQ + l) * EDIM + hd * DHEAD + m]);
        attn[((size_t)l * BATCH + b) * EDIM + hd * DHEAD + m] = f2b(xv + ov);
      }
    }
  }
}

// ---------------------------------------------------------------------------
extern "C" void kernel_launch(void* const* d_in, const int* in_sizes, int n_in,
                              void* d_out, int out_size, void* d_ws, size_t ws_size,
                              hipStream_t stream) {
  const float* query = (const float*)d_in[0];
  const float* Wq = (const float*)d_in[1];
  const float* bq = (const float*)d_in[2];
  const float* Wk = (const float*)d_in[3];
  const float* bk = (const float*)d_in[4];
  const float* Wv = (const float*)d_in[5];
  const float* bv = (const float*)d_in[6];
  const float* Wo = (const float*)d_in[7];
  const float* bo = (const float*)d_in[8];
  float* out = (float*)d_out;  // fp32 output

  unsigned short* xT = (unsigned short*)d_out;  // bf16 staging inside d_out

  char* ws = (char*)d_ws;
  const size_t SZ = (size_t)MROWS * EDIM * 2;  // 28,311,552
  unsigned short* qbuf = (unsigned short*)(ws);
  unsigned short* attnb = (unsigned short*)(ws + SZ);
  float* kvT  = (float*)(ws + 3 * SZ);                    // 3,145,728 B
  float* ksum = (float*)(ws + 3 * SZ + 3145728);          // 49,152 B
  unsigned short* wbf = (unsigned short*)(ws + 3 * SZ + 3145728 + 49152);

  // sin/cos table in the dead upper half of d_out (last used by attn_mfma,
  // overwritten only by the final gemm256<1> output store).
  float2* sct = (float2*)((char*)d_out + SZ);

  static bool attr_done = false;
  if (!attr_done) {
    (void)hipFuncSetAttribute((const void*)gemm256<0>,
                              hipFuncAttributeMaxDynamicSharedMemorySize, 65536);
    (void)hipFuncSetAttribute((const void*)gemm256<1>,
                              hipFuncAttributeMaxDynamicSharedMemorySize, 65536);
    (void)hipFuncSetAttribute((const void*)kv_fused,
                              hipFuncAttributeMaxDynamicSharedMemorySize, 93696);
    attr_done = true;
  }

  // conv_w (2304) + transpose_q (3456) + kv/ksum zero (780) + sct (9) = 6549
  prep<<<dim3(6549), 256, 0, stream>>>(query, Wq, Wk, Wv, Wo, wbf, xT, kvT, sct);

  // q projection: 144 row panels x 6 col panels = 864 blocks
  gemm256<0><<<dim3(864), dim3(512), 65536, stream>>>(xT, wbf, bq, qbuf, nullptr);

  // fused k/v projection + kv/ksum reduction: 96 heads x 3 l-chunks
  kv_fused<<<dim3(288), dim3(512), 93696, stream>>>(xT, wbf, bk, bv, sct, kvT, ksum);

  attn_mfma<<<dim3(L_SEQ / 128, 96), 256, 0, stream>>>(qbuf, kvT, ksum, xT, sct, attnb);

  // output projection: 144 x 6 = 864 blocks
  gemm256<1><<<dim3(864), dim3(512), 65536, stream>>>(
      attnb, wbf + 3 * (size_t)EDIM * EDIM, bo, nullptr, out);
}